// Round 2
// baseline (134.351 us; speedup 1.0000x reference)
//
#include <hip/hip_runtime.h>

#define L_N    50000
#define K_DIM  512
#define C_DIM  32
#define NROWS  64
#define KC     64                           // floats per row per chunk
#define NCHUNK (K_DIM / KC)                 // 8
#define NBLK   ((L_N + NROWS - 1) / NROWS)  // 782

// ws layout (floats): [0]=sum exp  [1..32]=sum exp*emb[c]  [33]=block counter (int)

__global__ __launch_bounds__(256, 4) void k_fused(
    const float* __restrict__ other,   // [L][512]
    const float* __restrict__ W12,     // [32][512]
    const float* __restrict__ b12,     // [32]
    const float* __restrict__ Wa,      // [96]
    const float* __restrict__ inputs,  // [256]
    const float* __restrict__ act_idx, // [64]
    const float* __restrict__ W11, const float* __restrict__ b11,
    const float* __restrict__ Wao, const float* __restrict__ bao,
    const float* __restrict__ W2,  const float* __restrict__ b2,
    const float* __restrict__ W3,  const float* __restrict__ b3,
    float* __restrict__ ws,
    float* __restrict__ out)           // [33]: r, samples[32]
{
    __shared__ float xs[2][NROWS * KC];     // 2 x 16 KB, double-buffered
    __shared__ float sred[4][NROWS];
    __shared__ float pbuf[NROWS];
    __shared__ int   elect;

    const int tid  = threadIdx.x;
    const int lane = tid & 63;
    const int wv   = tid >> 6;
    const int c0   = __builtin_amdgcn_readfirstlane(wv << 3);  // wave-uniform channels
    const int row0 = blockIdx.x * NROWS;

    // ---- staging geometry ----------------------------------------------
    // dest (linear, required by global_load_lds): float off = i*1024 + wv*256 + lane*4
    //   -> row = i*16 + wv*4 + (lane>>4), phys_slot = lane&15
    // physical slot p of row r holds logical slot p ^ (r & 15)  (16-slot XOR swizzle)
    const int grp  = lane >> 4;
    const int sl   = lane & 15;
    const int wl   = wv * 4 + grp;          // == row & 15 for all 4 of this thread's rows
    const int perm = sl ^ wl;               // logical slot to fetch from global
    const float* psrc[4];
    #pragma unroll
    for (int i = 0; i < 4; ++i) {
        int r = row0 + i * 16 + wl;
        if (r >= L_N) r = L_N - 1;          // tail clamp (weighted by p=0 later)
        psrc[i] = other + (size_t)r * K_DIM + (perm << 2);
    }

    #define STAGE(b, ck) do {                                                  \
        _Pragma("unroll")                                                      \
        for (int i = 0; i < 4; ++i) {                                          \
            __builtin_amdgcn_global_load_lds(                                  \
                (const __attribute__((address_space(1))) void*)(psrc[i] + (ck) * KC), \
                (__attribute__((address_space(3))) void*)(&xs[b][i * 1024 + wv * 256 + lane * 4]), \
                16, 0, 0);                                                     \
        }                                                                      \
    } while (0)

    float acc[8] = {0.f,0.f,0.f,0.f,0.f,0.f,0.f,0.f};

    STAGE(0, 0);
    __syncthreads();                         // buf0 ready
    int buf = 0;
    for (int ck = 0; ck < NCHUNK; ++ck) {
        if (ck + 1 < NCHUNK) STAGE(buf ^ 1, ck + 1);   // prefetch flies under compute
        const int k0 = ck * KC;
        #pragma unroll
        for (int kk4 = 0; kk4 < 16; ++kk4) {
            const int phys = (kk4 ^ sl) << 2;          // swizzled read -> banks spread
            const float4 xv = *(const float4*)&xs[buf][lane * KC + phys];
            const int k = k0 + (kk4 << 2);
            #pragma unroll
            for (int j = 0; j < 8; ++j) {
                const float4 wv4 = *(const float4*)&W12[(size_t)(c0 + j) * K_DIM + k];
                acc[j] = fmaf(xv.x, wv4.x, acc[j]);
                acc[j] = fmaf(xv.y, wv4.y, acc[j]);
                acc[j] = fmaf(xv.z, wv4.z, acc[j]);
                acc[j] = fmaf(xv.w, wv4.w, acc[j]);
            }
        }
        __syncthreads();                     // drains prefetch; frees buf for restage
        buf ^= 1;
    }

    // ---- scores (softmax shift-invariance removed rx·Wa and ba) ----------
    float sc = 0.f;
    #pragma unroll
    for (int j = 0; j < 8; ++j) {
        acc[j] += b12[c0 + j];
        sc = fmaf(fmaxf(acc[j], 0.f), Wa[64 + c0 + j], sc);
    }
    sred[wv][lane] = sc;
    __syncthreads();

    if (wv == 0) {
        const float s = sred[0][lane] + sred[1][lane] + sred[2][lane] + sred[3][lane];
        pbuf[lane] = (row0 + lane < L_N) ? __expf(s) : 0.f;
    }
    __syncthreads();
    const float p = pbuf[lane];

    // ---- weighted-emb butterfly all-reduce + atomics ----------------------
    float wacc[8];
    #pragma unroll
    for (int j = 0; j < 8; ++j) wacc[j] = p * acc[j];
    #pragma unroll
    for (int d = 1; d < 64; d <<= 1) {
        #pragma unroll
        for (int j = 0; j < 8; ++j) wacc[j] += __shfl_xor(wacc[j], d);
    }
    if (lane < 8) {
        float v = 0.f;
        #pragma unroll
        for (int j = 0; j < 8; ++j) v = (lane == j) ? wacc[j] : v;
        atomicAdd(ws + 1 + c0 + lane, v);
    }
    if (wv == 0) {
        float l = p;
        #pragma unroll
        for (int d = 1; d < 64; d <<= 1) l += __shfl_xor(l, d);
        if (lane == 0) atomicAdd(ws, l);
    }

    // ---- last-block election: fused final MLP ----------------------------
    __threadfence();
    if (tid == 0) {
        const int v = atomicAdd((int*)(ws + 33), 1);
        elect = (v == NBLK - 1);
    }
    __syncthreads();
    if (!elect) return;

    __shared__ float wsl[33];     // coherent snapshot of ws
    __shared__ float rm[32], z[32], xcat[96], h64[64];
    __shared__ int   amax;

    const int t = tid, hh = t >> 2, q = t & 3;
    if (t < 33) wsl[t] = atomicAdd(ws + t, 0.f);   // L2-coherent read
    __syncthreads();
    if (t < 32) rm[t] = fmaxf(wsl[1 + t] / wsl[0], 0.f);

    // input_x: 4 threads per output h, 80 k each
    float bp = 0.f;
    for (int i = 0; i < 80; ++i) {
        const int k = q * 80 + i;
        const float xv = (k < 256) ? inputs[k] : act_idx[k - 256];
        bp = fmaf(W11[hh * 320 + k], xv, bp);
    }
    bp += __shfl_xor(bp, 1);
    bp += __shfl_xor(bp, 2);
    __syncthreads();

    if (t < 32) {
        float zz = bao[t];
        for (int d = 0; d < 32; ++d) zz = fmaf(Wao[t * 32 + d], rm[d], zz);
        z[t] = zz;
    }
    __syncthreads();
    if (t == 0) {
        int bi = 0; float bv = z[0];
        for (int c = 1; c < 32; ++c) { if (z[c] > bv) { bv = z[c]; bi = c; } }
        amax = bi;                                   // first-max, matches jnp.argmax
    }
    __syncthreads();
    if (q == 0) xcat[hh] = fmaxf(bp + b11[hh], 0.f);
    if (t < 32) xcat[64 + t] = (t == amax) ? 1.f : 0.f;  // one_hot_st == samples
    __syncthreads();

    float dp = 0.f;
    for (int i = 0; i < 24; ++i) {
        const int k = q * 24 + i;
        dp = fmaf(W2[hh * 96 + k], xcat[k], dp);
    }
    dp += __shfl_xor(dp, 1);
    dp += __shfl_xor(dp, 2);
    if (q == 0) h64[hh] = fmaxf(dp + b2[hh], 0.f);
    __syncthreads();

    if (t == 0) {
        float r = b3[0];
        for (int i = 0; i < 64; ++i) r = fmaf(W3[i], h64[i], r);
        out[0] = r;
    }
    if (t < 32) out[1 + t] = (t == amax) ? 1.f : 0.f;
}

extern "C" void kernel_launch(void* const* d_in, const int* in_sizes, int n_in,
                              void* d_out, int out_size, void* d_ws, size_t ws_size,
                              hipStream_t stream) {
    const float* inputs  = (const float*)d_in[0];
    const float* act_idx = (const float*)d_in[1];
    const float* other   = (const float*)d_in[2];
    const float* W11     = (const float*)d_in[3];
    const float* b11     = (const float*)d_in[4];
    const float* W12     = (const float*)d_in[5];
    const float* b12     = (const float*)d_in[6];
    const float* Wa      = (const float*)d_in[7];
    // d_in[8] = ba : unused (softmax shift-invariant)
    const float* Wao     = (const float*)d_in[9];
    const float* bao     = (const float*)d_in[10];
    const float* W2      = (const float*)d_in[11];
    const float* b2      = (const float*)d_in[12];
    const float* W3      = (const float*)d_in[13];
    const float* b3      = (const float*)d_in[14];
    float* ws = (float*)d_ws;

    hipMemsetAsync(ws, 0, 34 * sizeof(float), stream);   // sums + counter
    k_fused<<<NBLK, 256, 0, stream>>>(other, W12, b12, Wa,
                                      inputs, act_idx, W11, b11,
                                      Wao, bao, W2, b2, W3, b3,
                                      ws, (float*)d_out);
}

// Round 3
// 115.547 us; speedup vs baseline: 1.1627x; 1.1627x over previous
//
#include <hip/hip_runtime.h>

#define L_N    50000
#define K_DIM  512
#define NROWS  64
#define KC     64                           // floats per row per chunk
#define NCHUNK (K_DIM / KC)                 // 8
#define NBLK   ((L_N + NROWS - 1) / NROWS)  // 782

typedef __attribute__((ext_vector_type(8))) short bf16x8;
typedef __attribute__((ext_vector_type(4))) float f32x4;

// split 8 f32 into truncated-bf16 hi + bf16(residual) lo; (h+l) recovers ~17 bits
__device__ __forceinline__ void split8(float4 a, float4 b, bf16x8& hi, bf16x8& lo) {
    float v[8] = {a.x, a.y, a.z, a.w, b.x, b.y, b.z, b.w};
    #pragma unroll
    for (int j = 0; j < 8; ++j) {
        unsigned u  = __float_as_uint(v[j]);
        unsigned hb = u & 0xFFFF0000u;
        float    lf = v[j] - __uint_as_float(hb);
        hi[j] = (short)(hb >> 16);
        lo[j] = (short)(__float_as_uint(lf) >> 16);
    }
}

// ws: [0]=sum exp  [1..32]=sum exp*emb[c]  [33]=block counter

__global__ __launch_bounds__(256, 3) void k_fused(
    const float* __restrict__ other,   // [L][512]
    const float* __restrict__ W12,     // [32][512]
    const float* __restrict__ b12,     // [32]
    const float* __restrict__ Wa,      // [96]
    const float* __restrict__ inputs,  // [256]
    const float* __restrict__ act_idx, // [64]
    const float* __restrict__ W11, const float* __restrict__ b11,
    const float* __restrict__ Wao, const float* __restrict__ bao,
    const float* __restrict__ W2,  const float* __restrict__ b2,
    const float* __restrict__ W3,  const float* __restrict__ b3,
    float* __restrict__ ws,
    float* __restrict__ out)           // [33]: r, samples[32]
{
    __shared__ float xs[2][NROWS * KC];     // 2 x 16 KB dbuf
    __shared__ float sred[4][32];
    __shared__ float pbuf[NROWS];
    __shared__ int   elect;

    const int tid  = threadIdx.x;
    const int lane = tid & 63;
    const int wv   = tid >> 6;
    const int cl   = lane & 15;             // MFMA col / ch-within-tile / row&15
    const int g    = lane >> 4;             // k-slice group
    const int rbase= (wv & 1) * 32;         // wave's 32-row half
    const int chW  = ((wv >> 1) << 4) + cl; // wave's channel (0..31)
    const int row0 = blockIdx.x * NROWS;

    // ---- staging geometry (validated in R1: linear dest, pre-swizzled src) ----
    const int sl   = cl;
    const int wl   = (wv << 2) + g;         // staged-row & 15
    const int perm = sl ^ wl;
    const float* psrc[4];
    #pragma unroll
    for (int i = 0; i < 4; ++i) {
        int r = row0 + i * 16 + wl;
        if (r >= L_N) r = L_N - 1;          // tail clamp (weight p=0 later)
        psrc[i] = other + (size_t)r * K_DIM + (perm << 2);
    }

    #define STAGE(b, ck) do {                                                  \
        _Pragma("unroll")                                                      \
        for (int i = 0; i < 4; ++i) {                                          \
            __builtin_amdgcn_global_load_lds(                                  \
                (const __attribute__((address_space(1))) void*)(psrc[i] + (ck) * KC), \
                (__attribute__((address_space(3))) void*)(&xs[b][i * 1024 + wv * 256 + lane * 4]), \
                16, 0, 0);                                                     \
        }                                                                      \
    } while (0)

    f32x4 acc[2] = {{0.f,0.f,0.f,0.f},{0.f,0.f,0.f,0.f}};

    STAGE(0, 0);
    __syncthreads();
    int buf = 0;
    for (int ck = 0; ck < NCHUNK; ++ck) {
        if (ck + 1 < NCHUNK) STAGE(buf ^ 1, ck + 1);
        // W fragments for both k-steps: per-lane VECTOR loads (L2-hot, no s_load path)
        float4 wr[2][2];
        #pragma unroll
        for (int s = 0; s < 2; ++s) {
            const float* wp = W12 + (size_t)chW * K_DIM + (ck * 2 + s) * 32 + (g << 3);
            wr[s][0] = *(const float4*)wp;
            wr[s][1] = *(const float4*)(wp + 4);
        }
        #pragma unroll
        for (int s = 0; s < 2; ++s) {
            bf16x8 bh, bl; split8(wr[s][0], wr[s][1], bh, bl);
            #pragma unroll
            for (int rt = 0; rt < 2; ++rt) {
                const int rowl  = rbase + rt * 16 + cl;       // LDS row (row&15==cl)
                const int sbase = s * 8 + (g << 1);           // logical float4-slot
                const float4 x0 = *(const float4*)&xs[buf][rowl * KC + (( sbase      ^ cl) << 2)];
                const float4 x1 = *(const float4*)&xs[buf][rowl * KC + (((sbase + 1) ^ cl) << 2)];
                bf16x8 ah, al; split8(x0, x1, ah, al);
                acc[rt] = __builtin_amdgcn_mfma_f32_16x16x32_bf16(ah, bh, acc[rt], 0, 0, 0);
                acc[rt] = __builtin_amdgcn_mfma_f32_16x16x32_bf16(al, bh, acc[rt], 0, 0, 0);
                acc[rt] = __builtin_amdgcn_mfma_f32_16x16x32_bf16(ah, bl, acc[rt], 0, 0, 0);
            }
        }
        __syncthreads();
        buf ^= 1;
    }

    // ---- emb (+bias), scores; C/D layout: row=g*4+i, col=cl ----
    const float b12v = b12[chW];
    const float wav  = Wa[64 + chW];        // shift-invariance removed rx·Wa and ba
    float e[2][4];
    #pragma unroll
    for (int rt = 0; rt < 2; ++rt) {
        float s4[4];
        #pragma unroll
        for (int i = 0; i < 4; ++i) {
            e[rt][i] = acc[rt][i] + b12v;
            s4[i] = fmaxf(e[rt][i], 0.f) * wav;
        }
        #pragma unroll
        for (int d = 1; d < 16; d <<= 1) {
            #pragma unroll
            for (int i = 0; i < 4; ++i) s4[i] += __shfl_xor(s4[i], d);
        }
        if (cl == 0)
            *(float4*)&sred[wv][rt * 16 + (g << 2)] = make_float4(s4[0], s4[1], s4[2], s4[3]);
    }
    __syncthreads();

    if (wv == 0) {
        const int r = lane;
        const float s = sred[r >> 5][r & 31] + sred[2 + (r >> 5)][r & 31];
        pbuf[r] = (row0 + r < L_N) ? __expf(s) : 0.f;
    }
    __syncthreads();

    // ---- weighted emb: part[ch] = sum_rows p*emb ----
    float part = 0.f;
    #pragma unroll
    for (int rt = 0; rt < 2; ++rt) {
        const float4 pv = *(const float4*)&pbuf[rbase + rt * 16 + (g << 2)];
        part += pv.x * e[rt][0] + pv.y * e[rt][1] + pv.z * e[rt][2] + pv.w * e[rt][3];
    }
    part += __shfl_xor(part, 16);
    part += __shfl_xor(part, 32);
    if (lane < 16) atomicAdd(ws + 1 + chW, part);
    if (wv == 0) {
        float l2 = pbuf[lane];
        #pragma unroll
        for (int d = 1; d < 64; d <<= 1) l2 += __shfl_xor(l2, d);
        if (lane == 0) atomicAdd(ws, l2);
    }

    // ---- last-block election: fused final MLP ----
    __threadfence();
    if (tid == 0) {
        const int v = atomicAdd((int*)(ws + 33), 1);
        elect = (v == NBLK - 1);
    }
    __syncthreads();
    if (!elect) return;

    __shared__ float wsl[33];
    __shared__ float rm[32], z[32], xcat[96], h64[64];
    __shared__ int   amax;

    const int t = tid, hh = t >> 2, q = t & 3;
    if (t < 33) wsl[t] = atomicAdd(ws + t, 0.f);   // coherent snapshot
    __syncthreads();
    if (t < 32) rm[t] = fmaxf(wsl[1 + t] / wsl[0], 0.f);

    float bp = 0.f;
    for (int i = 0; i < 80; ++i) {
        const int k = q * 80 + i;
        const float xv = (k < 256) ? inputs[k] : act_idx[k - 256];
        bp = fmaf(W11[hh * 320 + k], xv, bp);
    }
    bp += __shfl_xor(bp, 1);
    bp += __shfl_xor(bp, 2);
    __syncthreads();

    if (t < 32) {
        float zz = bao[t];
        for (int d = 0; d < 32; ++d) zz = fmaf(Wao[t * 32 + d], rm[d], zz);
        z[t] = zz;
    }
    __syncthreads();
    if (t == 0) {
        int bi = 0; float bv = z[0];
        for (int c = 1; c < 32; ++c) { if (z[c] > bv) { bv = z[c]; bi = c; } }
        amax = bi;                                   // first-max, matches jnp.argmax
    }
    __syncthreads();
    if (q == 0) xcat[hh] = fmaxf(bp + b11[hh], 0.f);
    if (t < 32) xcat[64 + t] = (t == amax) ? 1.f : 0.f;  // one_hot_st == samples
    __syncthreads();

    float dp = 0.f;
    for (int i = 0; i < 24; ++i) {
        const int k = q * 24 + i;
        dp = fmaf(W2[hh * 96 + k], xcat[k], dp);
    }
    dp += __shfl_xor(dp, 1);
    dp += __shfl_xor(dp, 2);
    if (q == 0) h64[hh] = fmaxf(dp + b2[hh], 0.f);
    __syncthreads();

    if (t == 0) {
        float r = b3[0];
        for (int i = 0; i < 64; ++i) r = fmaf(W3[i], h64[i], r);
        out[0] = r;
    }
    if (t < 32) out[1 + t] = (t == amax) ? 1.f : 0.f;
}

extern "C" void kernel_launch(void* const* d_in, const int* in_sizes, int n_in,
                              void* d_out, int out_size, void* d_ws, size_t ws_size,
                              hipStream_t stream) {
    const float* inputs  = (const float*)d_in[0];
    const float* act_idx = (const float*)d_in[1];
    const float* other   = (const float*)d_in[2];
    const float* W11     = (const float*)d_in[3];
    const float* b11     = (const float*)d_in[4];
    const float* W12     = (const float*)d_in[5];
    const float* b12     = (const float*)d_in[6];
    const float* Wa      = (const float*)d_in[7];
    // d_in[8] = ba : unused (softmax shift-invariant)
    const float* Wao     = (const float*)d_in[9];
    const float* bao     = (const float*)d_in[10];
    const float* W2      = (const float*)d_in[11];
    const float* b2      = (const float*)d_in[12];
    const float* W3      = (const float*)d_in[13];
    const float* b3      = (const float*)d_in[14];
    float* ws = (float*)d_ws;

    hipMemsetAsync(ws, 0, 34 * sizeof(float), stream);
    k_fused<<<NBLK, 256, 0, stream>>>(other, W12, b12, Wa,
                                      inputs, act_idx, W11, b11,
                                      Wao, bao, W2, b2, W3, b3,
                                      ws, (float*)d_out);
}

// Round 4
// 79.191 us; speedup vs baseline: 1.6965x; 1.4591x over previous
//
#include <hip/hip_runtime.h>

#define L_N    50000
#define K_DIM  512
#define NBLK   782            // 782 blocks * 64 rows = 50048 >= 50000
#define NSLOT  64             // atomic spread slots
// ws: float[33][64] accumulators (c*64+slot), int counter at ws[33*64]

typedef __attribute__((ext_vector_type(8))) short bf16x8;
typedef __attribute__((ext_vector_type(4))) float f32x4;

// split 8 f32 into truncated-bf16 hi + bf16(residual) lo  (validated R2: absmax 0.0)
__device__ __forceinline__ void split8(float4 a, float4 b, bf16x8& hi, bf16x8& lo) {
    float v[8] = {a.x, a.y, a.z, a.w, b.x, b.y, b.z, b.w};
    #pragma unroll
    for (int j = 0; j < 8; ++j) {
        unsigned u  = __float_as_uint(v[j]);
        unsigned hb = u & 0xFFFF0000u;
        float    lf = v[j] - __uint_as_float(hb);
        hi[j] = (short)(hb >> 16);
        lo[j] = (short)(__float_as_uint(lf) >> 16);
    }
}

__global__ __launch_bounds__(256, 2) void k_direct(
    const float* __restrict__ other,   // [L][512]
    const float* __restrict__ W12,     // [32][512]
    const float* __restrict__ b12,     // [32]
    const float* __restrict__ Wa,      // [96]
    const float* __restrict__ inputs,  // [256]
    const float* __restrict__ act_idx, // [64]
    const float* __restrict__ W11, const float* __restrict__ b11,
    const float* __restrict__ Wao, const float* __restrict__ bao,
    const float* __restrict__ W2,  const float* __restrict__ b2,
    const float* __restrict__ W3,  const float* __restrict__ b3,
    float* __restrict__ ws,
    float* __restrict__ out)           // [33]: r, samples[32]
{
    // W12 pre-split hi/lo, layout [kc 16][g 4][ch 32][8 bf16] (16B units)
    __shared__ short whi[16384];       // 32 KB
    __shared__ short wlo[16384];       // 32 KB
    __shared__ float sbuf[4][36];
    __shared__ int   elect;

    const int tid  = threadIdx.x;
    const int lane = tid & 63;
    const int wv   = tid >> 6;
    const int cl   = lane & 15;
    const int g    = lane >> 4;

    // ---- one-time: W12 -> LDS pre-split (no hot-loop reloads) ----
    {
        const int ch = tid >> 3, seg = tid & 7;
        const float* wp = W12 + (size_t)ch * K_DIM + seg * 64;
        #pragma unroll
        for (int j = 0; j < 8; ++j) {
            const float4 a = *(const float4*)(wp + j * 8);
            const float4 b = *(const float4*)(wp + j * 8 + 4);
            bf16x8 h8, l8; split8(a, b, h8, l8);
            const int k0 = seg * 64 + j * 8;
            const int u  = ((k0 >> 5) * 4 + ((k0 >> 3) & 3)) * 32 + ch;
            *(bf16x8*)&whi[u * 8] = h8;
            *(bf16x8*)&wlo[u * 8] = l8;
        }
    }
    __syncthreads();                    // the ONLY barrier before the epilogue

    // ---- hot loop: direct global->VGPR A-frags, LDS B-frags, no barriers ----
    const int wrow0 = (blockIdx.x * 4 + wv) * 16;
    int lrow = wrow0 + cl; if (lrow >= L_N) lrow = L_N - 1;   // tail clamp
    const float* xp = other + (size_t)lrow * K_DIM + g * 8;

    f32x4 acc0 = {0.f,0.f,0.f,0.f}, acc1 = {0.f,0.f,0.f,0.f};
    #pragma unroll 4
    for (int kc = 0; kc < 16; ++kc) {
        const float4 xa = *(const float4*)(xp + kc * 32);
        const float4 xb = *(const float4*)(xp + kc * 32 + 4);
        bf16x8 ah, al; split8(xa, xb, ah, al);
        const int u0 = ((kc * 4 + g) * 32 + cl) * 8;
        const bf16x8 bh0 = *(const bf16x8*)&whi[u0];
        const bf16x8 bl0 = *(const bf16x8*)&wlo[u0];
        const bf16x8 bh1 = *(const bf16x8*)&whi[u0 + 128];
        const bf16x8 bl1 = *(const bf16x8*)&wlo[u0 + 128];
        acc0 = __builtin_amdgcn_mfma_f32_16x16x32_bf16(ah, bh0, acc0, 0, 0, 0);
        acc0 = __builtin_amdgcn_mfma_f32_16x16x32_bf16(al, bh0, acc0, 0, 0, 0);
        acc0 = __builtin_amdgcn_mfma_f32_16x16x32_bf16(ah, bl0, acc0, 0, 0, 0);
        acc1 = __builtin_amdgcn_mfma_f32_16x16x32_bf16(ah, bh1, acc1, 0, 0, 0);
        acc1 = __builtin_amdgcn_mfma_f32_16x16x32_bf16(al, bh1, acc1, 0, 0, 0);
        acc1 = __builtin_amdgcn_mfma_f32_16x16x32_bf16(ah, bl1, acc1, 0, 0, 0);
    }

    // ---- epilogue, all in-wave: C row=(g*4+i), col=cl ----
    const float b0 = b12[cl],      b1 = b12[16 + cl];
    const float w0 = Wa[64 + cl],  w1 = Wa[80 + cl];   // shift-invariance: rx·Wa, ba dropped
    float e0[4], e1[4], s4[4];
    #pragma unroll
    for (int i = 0; i < 4; ++i) {
        e0[i] = acc0[i] + b0;
        e1[i] = acc1[i] + b1;
        s4[i] = fmaxf(e0[i], 0.f) * w0 + fmaxf(e1[i], 0.f) * w1;
    }
    #pragma unroll
    for (int d = 1; d < 16; d <<= 1) {
        #pragma unroll
        for (int i = 0; i < 4; ++i) s4[i] += __shfl_xor(s4[i], d);
    }
    float p4[4], ps = 0.f, m0 = 0.f, m1 = 0.f;
    #pragma unroll
    for (int i = 0; i < 4; ++i) {
        const int ra = wrow0 + g * 4 + i;
        p4[i] = (ra < L_N) ? __expf(s4[i]) : 0.f;
        ps += p4[i];
        m0 = fmaf(p4[i], e0[i], m0);
        m1 = fmaf(p4[i], e1[i], m1);
    }
    ps += __shfl_xor(ps, 16); ps += __shfl_xor(ps, 32);
    m0 += __shfl_xor(m0, 16); m0 += __shfl_xor(m0, 32);
    m1 += __shfl_xor(m1, 16); m1 += __shfl_xor(m1, 32);

    if (lane == 0)  sbuf[wv][0] = ps;
    if (lane < 16) { sbuf[wv][1 + cl] = m0; sbuf[wv][17 + cl] = m1; }
    __syncthreads();

    const int slot = blockIdx.x & (NSLOT - 1);
    if (wv == 0 && lane < 33) {
        const float v = sbuf[0][lane] + sbuf[1][lane] + sbuf[2][lane] + sbuf[3][lane];
        atomicAdd(ws + lane * NSLOT + slot, v);
    }

    // ---- last-block election ----
    if (tid == 0) {
        __threadfence();
        const int v = __hip_atomic_fetch_add((int*)(ws + 33 * NSLOT), 1,
                                             __ATOMIC_ACQ_REL, __HIP_MEMORY_SCOPE_AGENT);
        elect = (v == NBLK - 1);
    }
    __syncthreads();
    if (!elect) return;

    __shared__ float wsl[33];
    __shared__ float rm[32], z[32], xcat[96], h64[64];
    __shared__ int   amax;

    const int t = tid, hh = t >> 2, q = t & 3;
    if (t < 33) {
        float v = 0.f;
        #pragma unroll
        for (int s = 0; s < NSLOT; ++s)
            v += atomicAdd(ws + t * NSLOT + s, 0.f);   // coherent read (proven pattern)
        wsl[t] = v;
    }
    __syncthreads();
    if (t < 32) rm[t] = fmaxf(wsl[1 + t] / wsl[0], 0.f);

    float bp = 0.f;
    for (int i = 0; i < 80; ++i) {
        const int k = q * 80 + i;
        const float xv = (k < 256) ? inputs[k] : act_idx[k - 256];
        bp = fmaf(W11[hh * 320 + k], xv, bp);
    }
    bp += __shfl_xor(bp, 1);
    bp += __shfl_xor(bp, 2);
    __syncthreads();

    if (t < 32) {
        float zz = bao[t];
        for (int d = 0; d < 32; ++d) zz = fmaf(Wao[t * 32 + d], rm[d], zz);
        z[t] = zz;
    }
    __syncthreads();
    if (t == 0) {
        int bi = 0; float bv = z[0];
        for (int c = 1; c < 32; ++c) { if (z[c] > bv) { bv = z[c]; bi = c; } }
        amax = bi;                                    // first-max, matches jnp.argmax
    }
    __syncthreads();
    if (q == 0) xcat[hh] = fmaxf(bp + b11[hh], 0.f);
    if (t < 32) xcat[64 + t] = (t == amax) ? 1.f : 0.f;   // one_hot_st == samples
    __syncthreads();

    float dp = 0.f;
    for (int i = 0; i < 24; ++i) {
        const int k = q * 24 + i;
        dp = fmaf(W2[hh * 96 + k], xcat[k], dp);
    }
    dp += __shfl_xor(dp, 1);
    dp += __shfl_xor(dp, 2);
    if (q == 0) h64[hh] = fmaxf(dp + b2[hh], 0.f);
    __syncthreads();

    if (t == 0) {
        float r = b3[0];
        for (int i = 0; i < 64; ++i) r = fmaf(W3[i], h64[i], r);
        out[0] = r;
    }
    if (t < 32) out[1 + t] = (t == amax) ? 1.f : 0.f;
}

extern "C" void kernel_launch(void* const* d_in, const int* in_sizes, int n_in,
                              void* d_out, int out_size, void* d_ws, size_t ws_size,
                              hipStream_t stream) {
    const float* inputs  = (const float*)d_in[0];
    const float* act_idx = (const float*)d_in[1];
    const float* other   = (const float*)d_in[2];
    const float* W11     = (const float*)d_in[3];
    const float* b11     = (const float*)d_in[4];
    const float* W12     = (const float*)d_in[5];
    const float* b12     = (const float*)d_in[6];
    const float* Wa      = (const float*)d_in[7];
    // d_in[8] = ba : unused (softmax shift-invariant)
    const float* Wao     = (const float*)d_in[9];
    const float* bao     = (const float*)d_in[10];
    const float* W2      = (const float*)d_in[11];
    const float* b2      = (const float*)d_in[12];
    const float* W3      = (const float*)d_in[13];
    const float* b3      = (const float*)d_in[14];
    float* ws = (float*)d_ws;

    hipMemsetAsync(ws, 0, (33 * NSLOT + 1) * sizeof(float), stream);
    k_direct<<<NBLK, 256, 0, stream>>>(other, W12, b12, Wa,
                                       inputs, act_idx, W11, b11,
                                       Wao, bao, W2, b2, W3, b3,
                                       ws, (float*)d_out);
}

// Round 5
// 75.961 us; speedup vs baseline: 1.7687x; 1.0425x over previous
//
#include <hip/hip_runtime.h>

#define L_N    50000
#define K_DIM  512
#define NBLK   782            // 782 blocks * 64 rows = 50048 >= 50000
#define NSLOT  64             // atomic spread slots
// ws: float[33][64] accumulators (c*64+slot), int counter at ws[33*64]

typedef __attribute__((ext_vector_type(8))) short bf16x8;
typedef __attribute__((ext_vector_type(4))) float f32x4;

// split 8 f32 into truncated-bf16 hi + bf16(residual) lo  (validated R2-R4: absmax 0.0)
__device__ __forceinline__ void split8(float4 a, float4 b, bf16x8& hi, bf16x8& lo) {
    float v[8] = {a.x, a.y, a.z, a.w, b.x, b.y, b.z, b.w};
    #pragma unroll
    for (int j = 0; j < 8; ++j) {
        unsigned u  = __float_as_uint(v[j]);
        unsigned hb = u & 0xFFFF0000u;
        float    lf = v[j] - __uint_as_float(hb);
        hi[j] = (short)(hb >> 16);
        lo[j] = (short)(__float_as_uint(lf) >> 16);
    }
}

__global__ __launch_bounds__(256, 2) void k_direct(
    const float* __restrict__ other,   // [L][512]
    const float* __restrict__ W12,     // [32][512]
    const float* __restrict__ b12,     // [32]
    const float* __restrict__ Wa,      // [96]
    const float* __restrict__ inputs,  // [256]
    const float* __restrict__ act_idx, // [64]
    const float* __restrict__ W11, const float* __restrict__ b11,
    const float* __restrict__ Wao, const float* __restrict__ bao,
    const float* __restrict__ W2,  const float* __restrict__ b2,
    const float* __restrict__ W3,  const float* __restrict__ b3,
    float* __restrict__ ws,
    float* __restrict__ out)           // [33]: r, samples[32]
{
    // W12 pre-split hi/lo, permuted frag layout [kc 16][g 4][ch 32][8 bf16]
    // frag (kc,g,ch) = W[ch, kc*32 + {g*4+0..3, 16+g*4+0..3}]  (k-permutation,
    // matched exactly by the x loads -> dot product unchanged)
    __shared__ short whi[16384];       // 32 KB
    __shared__ short wlo[16384];       // 32 KB
    __shared__ float sbuf[4][36];
    __shared__ int   elect;

    const int tid  = threadIdx.x;
    const int lane = tid & 63;
    const int wv   = tid >> 6;
    const int cl   = lane & 15;
    const int g    = lane >> 4;

    // ---- one-time: W12 -> LDS pre-split (permuted) ----
    {
        const int ch = tid >> 3, sub = tid & 7;          // sub -> chunks {2sub, 2sub+1}
        #pragma unroll
        for (int c2 = 0; c2 < 2; ++c2) {
            const int kc = sub * 2 + c2;
            const float* wp = W12 + (size_t)ch * K_DIM + kc * 32;
            float4 f[8];
            #pragma unroll
            for (int s = 0; s < 8; ++s) f[s] = *(const float4*)(wp + s * 4);
            #pragma unroll
            for (int gg = 0; gg < 4; ++gg) {
                bf16x8 h8, l8; split8(f[gg], f[4 + gg], h8, l8);
                const int u = ((kc * 4 + gg) * 32 + ch) * 8;
                *(bf16x8*)&whi[u] = h8;
                *(bf16x8*)&wlo[u] = l8;
            }
        }
    }
    __syncthreads();                    // the ONLY barrier before the epilogue

    // ---- hot loop: 16-deep register prefetch per half-K, no barriers ----
    const int wrow0 = (blockIdx.x * 4 + wv) * 16;
    int lrow = wrow0 + cl; if (lrow >= L_N) lrow = L_N - 1;   // tail clamp
    const float* xp = other + (size_t)lrow * K_DIM + (g << 2); // row base + g*4 floats

    f32x4 acc0 = {0.f,0.f,0.f,0.f}, acc1 = {0.f,0.f,0.f,0.f};
    #pragma unroll
    for (int h = 0; h < 2; ++h) {
        // issue all 16 loads (64B-contiguous per row per instruction)
        float4 xr[16];
        #pragma unroll
        for (int i = 0; i < 16; ++i)
            xr[i] = *(const float4*)(xp + h * 256 + (i >> 1) * 32 + (i & 1) * 16);
        #pragma unroll
        for (int kc8 = 0; kc8 < 8; ++kc8) {
            const int kc = h * 8 + kc8;
            bf16x8 ah, al; split8(xr[kc8 * 2], xr[kc8 * 2 + 1], ah, al);
            const int u0 = ((kc * 4 + g) * 32 + cl) * 8;
            const bf16x8 bh0 = *(const bf16x8*)&whi[u0];
            const bf16x8 bl0 = *(const bf16x8*)&wlo[u0];
            const bf16x8 bh1 = *(const bf16x8*)&whi[u0 + 128];
            const bf16x8 bl1 = *(const bf16x8*)&wlo[u0 + 128];
            acc0 = __builtin_amdgcn_mfma_f32_16x16x32_bf16(ah, bh0, acc0, 0, 0, 0);
            acc0 = __builtin_amdgcn_mfma_f32_16x16x32_bf16(al, bh0, acc0, 0, 0, 0);
            acc0 = __builtin_amdgcn_mfma_f32_16x16x32_bf16(ah, bl0, acc0, 0, 0, 0);
            acc1 = __builtin_amdgcn_mfma_f32_16x16x32_bf16(ah, bh1, acc1, 0, 0, 0);
            acc1 = __builtin_amdgcn_mfma_f32_16x16x32_bf16(al, bh1, acc1, 0, 0, 0);
            acc1 = __builtin_amdgcn_mfma_f32_16x16x32_bf16(ah, bl1, acc1, 0, 0, 0);
        }
    }

    // ---- epilogue (validated R3/R4): C row=(g*4+i), col=cl ----
    const float b0 = b12[cl],      b1 = b12[16 + cl];
    const float w0 = Wa[64 + cl],  w1 = Wa[80 + cl];   // shift-invariance: rx·Wa, ba dropped
    float e0[4], e1[4], s4[4];
    #pragma unroll
    for (int i = 0; i < 4; ++i) {
        e0[i] = acc0[i] + b0;
        e1[i] = acc1[i] + b1;
        s4[i] = fmaxf(e0[i], 0.f) * w0 + fmaxf(e1[i], 0.f) * w1;
    }
    #pragma unroll
    for (int d = 1; d < 16; d <<= 1) {
        #pragma unroll
        for (int i = 0; i < 4; ++i) s4[i] += __shfl_xor(s4[i], d);
    }
    float p4[4], ps = 0.f, m0 = 0.f, m1 = 0.f;
    #pragma unroll
    for (int i = 0; i < 4; ++i) {
        const int ra = wrow0 + g * 4 + i;
        p4[i] = (ra < L_N) ? __expf(s4[i]) : 0.f;
        ps += p4[i];
        m0 = fmaf(p4[i], e0[i], m0);
        m1 = fmaf(p4[i], e1[i], m1);
    }
    ps += __shfl_xor(ps, 16); ps += __shfl_xor(ps, 32);
    m0 += __shfl_xor(m0, 16); m0 += __shfl_xor(m0, 32);
    m1 += __shfl_xor(m1, 16); m1 += __shfl_xor(m1, 32);

    if (lane == 0)  sbuf[wv][0] = ps;
    if (lane < 16) { sbuf[wv][1 + cl] = m0; sbuf[wv][17 + cl] = m1; }
    __syncthreads();

    const int slot = blockIdx.x & (NSLOT - 1);
    if (wv == 0 && lane < 33) {
        const float v = sbuf[0][lane] + sbuf[1][lane] + sbuf[2][lane] + sbuf[3][lane];
        atomicAdd(ws + lane * NSLOT + slot, v);
    }

    // ---- last-block election ----
    if (tid == 0) {
        __threadfence();
        const int v = __hip_atomic_fetch_add((int*)(ws + 33 * NSLOT), 1,
                                             __ATOMIC_ACQ_REL, __HIP_MEMORY_SCOPE_AGENT);
        elect = (v == NBLK - 1);
    }
    __syncthreads();
    if (!elect) return;

    __shared__ float wsl[33];
    __shared__ float rm[32], z[32], xcat[96], h64[64];
    __shared__ int   amax;

    const int t = tid, hh = t >> 2, q = t & 3;
    if (t < 33) {
        float v = 0.f;
        #pragma unroll
        for (int s = 0; s < NSLOT; ++s)
            v += atomicAdd(ws + t * NSLOT + s, 0.f);   // coherent read (proven pattern)
        wsl[t] = v;
    }
    __syncthreads();
    if (t < 32) rm[t] = fmaxf(wsl[1 + t] / wsl[0], 0.f);

    float bp = 0.f;
    for (int i = 0; i < 80; ++i) {
        const int k = q * 80 + i;
        const float xv = (k < 256) ? inputs[k] : act_idx[k - 256];
        bp = fmaf(W11[hh * 320 + k], xv, bp);
    }
    bp += __shfl_xor(bp, 1);
    bp += __shfl_xor(bp, 2);
    __syncthreads();

    if (t < 32) {
        float zz = bao[t];
        for (int d = 0; d < 32; ++d) zz = fmaf(Wao[t * 32 + d], rm[d], zz);
        z[t] = zz;
    }
    __syncthreads();
    if (t == 0) {
        int bi = 0; float bv = z[0];
        for (int c = 1; c < 32; ++c) { if (z[c] > bv) { bv = z[c]; bi = c; } }
        amax = bi;                                    // first-max, matches jnp.argmax
    }
    __syncthreads();
    if (q == 0) xcat[hh] = fmaxf(bp + b11[hh], 0.f);
    if (t < 32) xcat[64 + t] = (t == amax) ? 1.f : 0.f;   // one_hot_st == samples
    __syncthreads();

    float dp = 0.f;
    for (int i = 0; i < 24; ++i) {
        const int k = q * 24 + i;
        dp = fmaf(W2[hh * 96 + k], xcat[k], dp);
    }
    dp += __shfl_xor(dp, 1);
    dp += __shfl_xor(dp, 2);
    if (q == 0) h64[hh] = fmaxf(dp + b2[hh], 0.f);
    __syncthreads();

    if (t == 0) {
        float r = b3[0];
        for (int i = 0; i < 64; ++i) r = fmaf(W3[i], h64[i], r);
        out[0] = r;
    }
    if (t < 32) out[1 + t] = (t == amax) ? 1.f : 0.f;
}

extern "C" void kernel_launch(void* const* d_in, const int* in_sizes, int n_in,
                              void* d_out, int out_size, void* d_ws, size_t ws_size,
                              hipStream_t stream) {
    const float* inputs  = (const float*)d_in[0];
    const float* act_idx = (const float*)d_in[1];
    const float* other   = (const float*)d_in[2];
    const float* W11     = (const float*)d_in[3];
    const float* b11     = (const float*)d_in[4];
    const float* W12     = (const float*)d_in[5];
    const float* b12     = (const float*)d_in[6];
    const float* Wa      = (const float*)d_in[7];
    // d_in[8] = ba : unused (softmax shift-invariant)
    const float* Wao     = (const float*)d_in[9];
    const float* bao     = (const float*)d_in[10];
    const float* W2      = (const float*)d_in[11];
    const float* b2      = (const float*)d_in[12];
    const float* W3      = (const float*)d_in[13];
    const float* b3      = (const float*)d_in[14];
    float* ws = (float*)d_ws;

    hipMemsetAsync(ws, 0, (33 * NSLOT + 1) * sizeof(float), stream);
    k_direct<<<NBLK, 256, 0, stream>>>(other, W12, b12, Wa,
                                       inputs, act_idx, W11, b11,
                                       Wao, bao, W2, b2, W3, b3,
                                       ws, (float*)d_out);
}

// Round 6
// 45.030 us; speedup vs baseline: 2.9836x; 1.6869x over previous
//
#include <hip/hip_runtime.h>

#define L_N    50000
#define K_DIM  512
#define NTILE  782             // 782 tiles * 64 rows = 50048 >= 50000
#define GRID1  256             // persistent: one block per CU
// ws: float[256][33] per-block partials (no atomics anywhere)

typedef __attribute__((ext_vector_type(8))) short bf16x8;
typedef __attribute__((ext_vector_type(4))) float f32x4;

// split 8 f32 into truncated-bf16 hi + bf16(residual) lo  (validated R2-R5: absmax 0.0)
__device__ __forceinline__ void split8(float4 a, float4 b, bf16x8& hi, bf16x8& lo) {
    float v[8] = {a.x, a.y, a.z, a.w, b.x, b.y, b.z, b.w};
    #pragma unroll
    for (int j = 0; j < 8; ++j) {
        unsigned u  = __float_as_uint(v[j]);
        unsigned hb = u & 0xFFFF0000u;
        float    lf = v[j] - __uint_as_float(hb);
        hi[j] = (short)(hb >> 16);
        lo[j] = (short)(__float_as_uint(lf) >> 16);
    }
}

__global__ __launch_bounds__(256, 1) void k_part(
    const float* __restrict__ other,   // [L][512]
    const float* __restrict__ W12,     // [32][512]
    const float* __restrict__ b12,     // [32]
    const float* __restrict__ Wa,      // [96]
    float* __restrict__ ws)            // [256][33]
{
    // W12 pre-split hi/lo, permuted frag layout [kc 16][g 4][ch 32][8 bf16]
    // frag (kc,g,ch) = W[ch, kc*32 + {g*4+0..3, 16+g*4+0..3}] (validated R4/R5)
    __shared__ short whi[16384];       // 32 KB
    __shared__ short wlo[16384];       // 32 KB
    __shared__ float sbuf[4][34];

    const int tid  = threadIdx.x;
    const int lane = tid & 63;
    const int wv   = tid >> 6;
    const int cl   = lane & 15;
    const int g    = lane >> 4;

    // ---- one-time per CU: W12 -> LDS pre-split (was once per 64 rows) ----
    {
        const int ch = tid >> 3, sub = tid & 7;
        #pragma unroll
        for (int c2 = 0; c2 < 2; ++c2) {
            const int kc = sub * 2 + c2;
            const float* wp = W12 + (size_t)ch * K_DIM + kc * 32;
            float4 f[8];
            #pragma unroll
            for (int s = 0; s < 8; ++s) f[s] = *(const float4*)(wp + s * 4);
            #pragma unroll
            for (int gg = 0; gg < 4; ++gg) {
                bf16x8 h8, l8; split8(f[gg], f[4 + gg], h8, l8);
                const int u = ((kc * 4 + gg) * 32 + ch) * 8;
                *(bf16x8*)&whi[u] = h8;
                *(bf16x8*)&wlo[u] = l8;
            }
        }
    }
    __syncthreads();

    // ---- static tile partition: 14 blocks x 4 tiles + 242 x 3 ----
    const int b   = blockIdx.x;
    const int tb0 = b * 3 + (b < 14 ? b : 14);
    const int cnt = 3 + (b < 14 ? 1 : 0);

    const float b0 = b12[cl],     b1 = b12[16 + cl];
    const float w0 = Wa[64 + cl], w1 = Wa[80 + cl];  // shift-invariance: rx·Wa, ba dropped

    float rps = 0.f, rm0 = 0.f, rm1 = 0.f;           // running per-lane partials
    float4 xa[16], xb[16];                           // named bufs: static indexing

    #define ROWPTR(t) ({ int _r = (tb0 + (t)) * 64 + wv * 16 + cl;              \
                         if (_r >= L_N) _r = L_N - 1;                           \
                         other + (size_t)_r * K_DIM + (g << 2); })

    #define ISSUE(dst, base, h) do {                                           \
        _Pragma("unroll")                                                      \
        for (int i = 0; i < 16; ++i)                                           \
            dst[i] = *(const float4*)((base) + (h) * 256 + (i >> 1) * 32 + (i & 1) * 16); \
    } while (0)

    #define CONSUME(buf, h) do {                                               \
        _Pragma("unroll")                                                      \
        for (int kc8 = 0; kc8 < 8; ++kc8) {                                    \
            const int kc = (h) * 8 + kc8;                                      \
            bf16x8 ah, al; split8(buf[kc8 * 2], buf[kc8 * 2 + 1], ah, al);     \
            const int u0 = ((kc * 4 + g) * 32 + cl) * 8;                       \
            const bf16x8 bh0 = *(const bf16x8*)&whi[u0];                       \
            const bf16x8 bl0 = *(const bf16x8*)&wlo[u0];                       \
            const bf16x8 bh1 = *(const bf16x8*)&whi[u0 + 128];                 \
            const bf16x8 bl1 = *(const bf16x8*)&wlo[u0 + 128];                 \
            acc0 = __builtin_amdgcn_mfma_f32_16x16x32_bf16(ah, bh0, acc0, 0, 0, 0); \
            acc0 = __builtin_amdgcn_mfma_f32_16x16x32_bf16(al, bh0, acc0, 0, 0, 0); \
            acc0 = __builtin_amdgcn_mfma_f32_16x16x32_bf16(ah, bl0, acc0, 0, 0, 0); \
            acc1 = __builtin_amdgcn_mfma_f32_16x16x32_bf16(ah, bh1, acc1, 0, 0, 0); \
            acc1 = __builtin_amdgcn_mfma_f32_16x16x32_bf16(al, bh1, acc1, 0, 0, 0); \
            acc1 = __builtin_amdgcn_mfma_f32_16x16x32_bf16(ah, bl1, acc1, 0, 0, 0); \
        }                                                                      \
    } while (0)

    const float* xp_cur = ROWPTR(0);
    ISSUE(xa, xp_cur, 0);                            // preload tile0 half0

    for (int t = 0; t < cnt; ++t) {
        const float* xp_nxt = (t + 1 < cnt) ? ROWPTR(t + 1) : xp_cur;

        ISSUE(xb, xp_cur, 1);                        // half1 in flight
        f32x4 acc0 = {0.f,0.f,0.f,0.f}, acc1 = {0.f,0.f,0.f,0.f};
        CONSUME(xa, 0);
        if (t + 1 < cnt) ISSUE(xa, xp_nxt, 0);       // next tile half0 in flight
        CONSUME(xb, 1);

        // ---- per-tile epilogue (validated): C row=(g*4+i), col=cl ----
        float e0[4], e1[4], s4[4];
        #pragma unroll
        for (int i = 0; i < 4; ++i) {
            e0[i] = acc0[i] + b0;
            e1[i] = acc1[i] + b1;
            s4[i] = fmaxf(e0[i], 0.f) * w0 + fmaxf(e1[i], 0.f) * w1;
        }
        #pragma unroll
        for (int d = 1; d < 16; d <<= 1) {
            #pragma unroll
            for (int i = 0; i < 4; ++i) s4[i] += __shfl_xor(s4[i], d);
        }
        const int wrow0 = (tb0 + t) * 64 + wv * 16;
        #pragma unroll
        for (int i = 0; i < 4; ++i) {
            const int ra = wrow0 + g * 4 + i;
            const float p = (ra < L_N) ? __expf(s4[i]) : 0.f;
            rps += p;
            rm0 = fmaf(p, e0[i], rm0);
            rm1 = fmaf(p, e1[i], rm1);
        }
        xp_cur = xp_nxt;
    }

    // ---- one reduce + one plain store per block ----
    rps += __shfl_xor(rps, 16); rps += __shfl_xor(rps, 32);
    rm0 += __shfl_xor(rm0, 16); rm0 += __shfl_xor(rm0, 32);
    rm1 += __shfl_xor(rm1, 16); rm1 += __shfl_xor(rm1, 32);
    if (lane == 0)  sbuf[wv][0] = rps;
    if (lane < 16) { sbuf[wv][1 + cl] = rm0; sbuf[wv][17 + cl] = rm1; }
    __syncthreads();
    if (wv == 0 && lane < 33)
        ws[b * 33 + lane] = sbuf[0][lane] + sbuf[1][lane] + sbuf[2][lane] + sbuf[3][lane];
}

__global__ __launch_bounds__(256) void k_final(
    const float* __restrict__ ws,       // [256][33]
    const float* __restrict__ inputs,   // [256]
    const float* __restrict__ act_idx,  // [64]
    const float* __restrict__ W11, const float* __restrict__ b11,
    const float* __restrict__ Wao, const float* __restrict__ bao,
    const float* __restrict__ W2,  const float* __restrict__ b2,
    const float* __restrict__ W3,  const float* __restrict__ b3,
    float* __restrict__ out)            // [33]: r, samples[32]
{
    __shared__ float wsl[33];
    __shared__ float rm[32], z[32], xcat[96], h64[64];
    __shared__ int   amax;

    const int t = threadIdx.x, hh = t >> 2, q = t & 3;
    if (t < 33) {                        // prior-kernel stores visible at kernel boundary
        float v = 0.f;
        for (int s = 0; s < GRID1; ++s) v += ws[s * 33 + t];
        wsl[t] = v;
    }
    __syncthreads();
    if (t < 32) rm[t] = fmaxf(wsl[1 + t] / wsl[0], 0.f);

    float bp = 0.f;
    for (int i = 0; i < 80; ++i) {
        const int k = q * 80 + i;
        const float xv = (k < 256) ? inputs[k] : act_idx[k - 256];
        bp = fmaf(W11[hh * 320 + k], xv, bp);
    }
    bp += __shfl_xor(bp, 1);
    bp += __shfl_xor(bp, 2);
    __syncthreads();

    if (t < 32) {
        float zz = bao[t];
        for (int d = 0; d < 32; ++d) zz = fmaf(Wao[t * 32 + d], rm[d], zz);
        z[t] = zz;
    }
    __syncthreads();
    if (t == 0) {
        int bi = 0; float bv = z[0];
        for (int c = 1; c < 32; ++c) { if (z[c] > bv) { bv = z[c]; bi = c; } }
        amax = bi;                                    // first-max, matches jnp.argmax
    }
    __syncthreads();
    if (q == 0) xcat[hh] = fmaxf(bp + b11[hh], 0.f);
    if (t < 32) xcat[64 + t] = (t == amax) ? 1.f : 0.f;   // one_hot_st == samples
    __syncthreads();

    float dp = 0.f;
    for (int i = 0; i < 24; ++i) {
        const int k = q * 24 + i;
        dp = fmaf(W2[hh * 96 + k], xcat[k], dp);
    }
    dp += __shfl_xor(dp, 1);
    dp += __shfl_xor(dp, 2);
    if (q == 0) h64[hh] = fmaxf(dp + b2[hh], 0.f);
    __syncthreads();

    if (t == 0) {
        float r = b3[0];
        for (int i = 0; i < 64; ++i) r = fmaf(W3[i], h64[i], r);
        out[0] = r;
    }
    if (t < 32) out[1 + t] = (t == amax) ? 1.f : 0.f;
}

extern "C" void kernel_launch(void* const* d_in, const int* in_sizes, int n_in,
                              void* d_out, int out_size, void* d_ws, size_t ws_size,
                              hipStream_t stream) {
    const float* inputs  = (const float*)d_in[0];
    const float* act_idx = (const float*)d_in[1];
    const float* other   = (const float*)d_in[2];
    const float* W11     = (const float*)d_in[3];
    const float* b11     = (const float*)d_in[4];
    const float* W12     = (const float*)d_in[5];
    const float* b12     = (const float*)d_in[6];
    const float* Wa      = (const float*)d_in[7];
    // d_in[8] = ba : unused (softmax shift-invariant)
    const float* Wao     = (const float*)d_in[9];
    const float* bao     = (const float*)d_in[10];
    const float* W2      = (const float*)d_in[11];
    const float* b2      = (const float*)d_in[12];
    const float* W3      = (const float*)d_in[13];
    const float* b3      = (const float*)d_in[14];
    float* ws = (float*)d_ws;

    // every ws slot k_final reads is written by k_part -> no memset needed
    k_part<<<GRID1, 256, 0, stream>>>(other, W12, b12, Wa, ws);
    k_final<<<1, 256, 0, stream>>>(ws, inputs, act_idx, W11, b11,
                                   Wao, bao, W2, b2, W3, b3, (float*)d_out);
}

// Round 7
// 43.885 us; speedup vs baseline: 3.0614x; 1.0261x over previous
//
#include <hip/hip_runtime.h>

#define L_N    50000
#define K_DIM  512
#define GRID1  256             // persistent: one block per CU
#define SB()   __builtin_amdgcn_sched_barrier(0)
// ws: float[256][33] per-block partials (no atomics anywhere)

typedef __attribute__((ext_vector_type(8))) short bf16x8;
typedef __attribute__((ext_vector_type(4))) float f32x4;

// split 8 f32 into truncated-bf16 hi + bf16(residual) lo  (validated R2-R6: absmax 0.0)
__device__ __forceinline__ void split8(float4 a, float4 b, bf16x8& hi, bf16x8& lo) {
    float v[8] = {a.x, a.y, a.z, a.w, b.x, b.y, b.z, b.w};
    #pragma unroll
    for (int j = 0; j < 8; ++j) {
        unsigned u  = __float_as_uint(v[j]);
        unsigned hb = u & 0xFFFF0000u;
        float    lf = v[j] - __uint_as_float(hb);
        hi[j] = (short)(hb >> 16);
        lo[j] = (short)(__float_as_uint(lf) >> 16);
    }
}

__global__ __launch_bounds__(256, 1) void k_part(
    const float* __restrict__ other,   // [L][512]
    const float* __restrict__ W12,     // [32][512]
    const float* __restrict__ b12,     // [32]
    const float* __restrict__ Wa,      // [96]
    float* __restrict__ ws)            // [256][33]
{
    // W12 pre-split hi/lo, permuted frag layout [kc 16][g 4][ch 32][8 bf16]
    // frag (kc,g,ch) = W[ch, kc*32 + {g*4+0..3, 16+g*4+0..3}] (validated R4-R6)
    __shared__ short whi[16384];       // 32 KB
    __shared__ short wlo[16384];       // 32 KB
    __shared__ float sbuf[4][34];

    const int tid  = threadIdx.x;
    const int lane = tid & 63;
    const int wv   = tid >> 6;
    const int cl   = lane & 15;
    const int g    = lane >> 4;

    // ---- one-time per CU: W12 -> LDS pre-split ----
    {
        const int ch = tid >> 3, sub = tid & 7;
        #pragma unroll
        for (int c2 = 0; c2 < 2; ++c2) {
            const int kc = sub * 2 + c2;
            const float* wp = W12 + (size_t)ch * K_DIM + kc * 32;
            float4 f[8];
            #pragma unroll
            for (int s = 0; s < 8; ++s) f[s] = *(const float4*)(wp + s * 4);
            #pragma unroll
            for (int gg = 0; gg < 4; ++gg) {
                bf16x8 h8, l8; split8(f[gg], f[4 + gg], h8, l8);
                const int u = ((kc * 4 + gg) * 32 + ch) * 8;
                *(bf16x8*)&whi[u] = h8;
                *(bf16x8*)&wlo[u] = l8;
            }
        }
    }
    __syncthreads();

    // ---- static tile partition: 14 blocks x 4 tiles + 242 x 3 (validated R6) ----
    const int b   = blockIdx.x;
    const int tb0 = b * 3 + (b < 14 ? b : 14);
    const int cnt = 3 + (b < 14 ? 1 : 0);

    const float b0 = b12[cl],     b1 = b12[16 + cl];
    const float w0 = Wa[64 + cl], w1 = Wa[80 + cl];  // shift-invariance: rx·Wa, ba dropped

    float rps = 0.f, rm0 = 0.f, rm1 = 0.f;           // running per-lane partials
    float4 xa[16], xb[16];                           // named bufs: static indexing

    #define ROWPTR(t) ({ int _r = (tb0 + (t)) * 64 + wv * 16 + cl;              \
                         if (_r >= L_N) _r = L_N - 1;                           \
                         other + (size_t)_r * K_DIM + (g << 2); })

    #define ISSUE(dst, base, h) do {                                           \
        _Pragma("unroll")                                                      \
        for (int i = 0; i < 16; ++i)                                           \
            dst[i] = *(const float4*)((base) + (h) * 256 + (i >> 1) * 32 + (i & 1) * 16); \
    } while (0)

    #define CONSUME(buf, h) do {                                               \
        _Pragma("unroll")                                                      \
        for (int kc8 = 0; kc8 < 8; ++kc8) {                                    \
            const int kc = (h) * 8 + kc8;                                      \
            bf16x8 ah, al; split8(buf[kc8 * 2], buf[kc8 * 2 + 1], ah, al);     \
            const int u0 = ((kc * 4 + g) * 32 + cl) * 8;                       \
            const bf16x8 bh0 = *(const bf16x8*)&whi[u0];                       \
            const bf16x8 bl0 = *(const bf16x8*)&wlo[u0];                       \
            const bf16x8 bh1 = *(const bf16x8*)&whi[u0 + 128];                 \
            const bf16x8 bl1 = *(const bf16x8*)&wlo[u0 + 128];                 \
            acc0 = __builtin_amdgcn_mfma_f32_16x16x32_bf16(ah, bh0, acc0, 0, 0, 0); \
            acc0 = __builtin_amdgcn_mfma_f32_16x16x32_bf16(al, bh0, acc0, 0, 0, 0); \
            acc0 = __builtin_amdgcn_mfma_f32_16x16x32_bf16(ah, bl0, acc0, 0, 0, 0); \
            acc1 = __builtin_amdgcn_mfma_f32_16x16x32_bf16(ah, bh1, acc1, 0, 0, 0); \
            acc1 = __builtin_amdgcn_mfma_f32_16x16x32_bf16(al, bh1, acc1, 0, 0, 0); \
            acc1 = __builtin_amdgcn_mfma_f32_16x16x32_bf16(ah, bl1, acc1, 0, 0, 0); \
        }                                                                      \
    } while (0)

    const float* xp_cur = ROWPTR(0);
    ISSUE(xa, xp_cur, 0);                            // preload tile0 half0
    SB();                                            // pin: batch issued before anything else

    for (int t = 0; t < cnt; ++t) {
        const float* xp_nxt = (t + 1 < cnt) ? ROWPTR(t + 1) : xp_cur;

        ISSUE(xb, xp_cur, 1);                        // 16 loads in flight
        SB();                                        // pin: xb batch precedes consume region
        f32x4 acc0 = {0.f,0.f,0.f,0.f}, acc1 = {0.f,0.f,0.f,0.f};
        CONSUME(xa, 0);
        if (t + 1 < cnt) ISSUE(xa, xp_nxt, 0);       // WAR-renamable; overlaps consume xb
        SB();                                        // pin: next-tile batch precedes consume xb
        CONSUME(xb, 1);

        // ---- per-tile epilogue (validated): C row=(g*4+i), col=cl ----
        float e0[4], e1[4], s4[4];
        #pragma unroll
        for (int i = 0; i < 4; ++i) {
            e0[i] = acc0[i] + b0;
            e1[i] = acc1[i] + b1;
            s4[i] = fmaxf(e0[i], 0.f) * w0 + fmaxf(e1[i], 0.f) * w1;
        }
        #pragma unroll
        for (int d = 1; d < 16; d <<= 1) {
            #pragma unroll
            for (int i = 0; i < 4; ++i) s4[i] += __shfl_xor(s4[i], d);
        }
        const int wrow0 = (tb0 + t) * 64 + wv * 16;
        #pragma unroll
        for (int i = 0; i < 4; ++i) {
            const int ra = wrow0 + g * 4 + i;
            const float p = (ra < L_N) ? __expf(s4[i]) : 0.f;
            rps += p;
            rm0 = fmaf(p, e0[i], rm0);
            rm1 = fmaf(p, e1[i], rm1);
        }
        xp_cur = xp_nxt;
    }

    // ---- one reduce + one plain store per block ----
    rps += __shfl_xor(rps, 16); rps += __shfl_xor(rps, 32);
    rm0 += __shfl_xor(rm0, 16); rm0 += __shfl_xor(rm0, 32);
    rm1 += __shfl_xor(rm1, 16); rm1 += __shfl_xor(rm1, 32);
    if (lane == 0)  sbuf[wv][0] = rps;
    if (lane < 16) { sbuf[wv][1 + cl] = rm0; sbuf[wv][17 + cl] = rm1; }
    __syncthreads();
    if (wv == 0 && lane < 33)
        ws[b * 33 + lane] = sbuf[0][lane] + sbuf[1][lane] + sbuf[2][lane] + sbuf[3][lane];
}

__global__ __launch_bounds__(256) void k_final(
    const float* __restrict__ ws,       // [256][33]
    const float* __restrict__ inputs,   // [256]
    const float* __restrict__ act_idx,  // [64]
    const float* __restrict__ W11, const float* __restrict__ b11,
    const float* __restrict__ Wao, const float* __restrict__ bao,
    const float* __restrict__ W2,  const float* __restrict__ b2,
    const float* __restrict__ W3,  const float* __restrict__ b3,
    float* __restrict__ out)            // [33]: r, samples[32]
{
    __shared__ float wsl[33];
    __shared__ float rm[32], z[32], xcat[96], h64[64];
    __shared__ int   amax;

    const int t = threadIdx.x, hh = t >> 2, q = t & 3;
    if (t < 33) {                        // prior-kernel stores visible at kernel boundary
        float v = 0.f;
        for (int s = 0; s < GRID1; ++s) v += ws[s * 33 + t];
        wsl[t] = v;
    }
    __syncthreads();
    if (t < 32) rm[t] = fmaxf(wsl[1 + t] / wsl[0], 0.f);

    float bp = 0.f;
    for (int i = 0; i < 80; ++i) {
        const int k = q * 80 + i;
        const float xv = (k < 256) ? inputs[k] : act_idx[k - 256];
        bp = fmaf(W11[hh * 320 + k], xv, bp);
    }
    bp += __shfl_xor(bp, 1);
    bp += __shfl_xor(bp, 2);
    __syncthreads();

    if (t < 32) {
        float zz = bao[t];
        for (int d = 0; d < 32; ++d) zz = fmaf(Wao[t * 32 + d], rm[d], zz);
        z[t] = zz;
    }
    __syncthreads();
    if (t == 0) {
        int bi = 0; float bv = z[0];
        for (int c = 1; c < 32; ++c) { if (z[c] > bv) { bv = z[c]; bi = c; } }
        amax = bi;                                    // first-max, matches jnp.argmax
    }
    __syncthreads();
    if (q == 0) xcat[hh] = fmaxf(bp + b11[hh], 0.f);
    if (t < 32) xcat[64 + t] = (t == amax) ? 1.f : 0.f;   // one_hot_st == samples
    __syncthreads();

    float dp = 0.f;
    for (int i = 0; i < 24; ++i) {
        const int k = q * 24 + i;
        dp = fmaf(W2[hh * 96 + k], xcat[k], dp);
    }
    dp += __shfl_xor(dp, 1);
    dp += __shfl_xor(dp, 2);
    if (q == 0) h64[hh] = fmaxf(dp + b2[hh], 0.f);
    __syncthreads();

    if (t == 0) {
        float r = b3[0];
        for (int i = 0; i < 64; ++i) r = fmaf(W3[i], h64[i], r);
        out[0] = r;
    }
    if (t < 32) out[1 + t] = (t == amax) ? 1.f : 0.f;
}

extern "C" void kernel_launch(void* const* d_in, const int* in_sizes, int n_in,
                              void* d_out, int out_size, void* d_ws, size_t ws_size,
                              hipStream_t stream) {
    const float* inputs  = (const float*)d_in[0];
    const float* act_idx = (const float*)d_in[1];
    const float* other   = (const float*)d_in[2];
    const float* W11     = (const float*)d_in[3];
    const float* b11     = (const float*)d_in[4];
    const float* W12     = (const float*)d_in[5];
    const float* b12     = (const float*)d_in[6];
    const float* Wa      = (const float*)d_in[7];
    // d_in[8] = ba : unused (softmax shift-invariant)
    const float* Wao     = (const float*)d_in[9];
    const float* bao     = (const float*)d_in[10];
    const float* W2      = (const float*)d_in[11];
    const float* b2      = (const float*)d_in[12];
    const float* W3      = (const float*)d_in[13];
    const float* b3      = (const float*)d_in[14];
    float* ws = (float*)d_ws;

    // every ws slot k_final reads is written by k_part -> no memset needed
    k_part<<<GRID1, 256, 0, stream>>>(other, W12, b12, Wa, ws);
    k_final<<<1, 256, 0, stream>>>(ws, inputs, act_idx, W11, b11,
                                   Wao, bao, W2, b2, W3, b3, (float*)d_out);
}

// Round 8
// 39.125 us; speedup vs baseline: 3.4339x; 1.1217x over previous
//
#include <hip/hip_runtime.h>

#define L_N    50000
#define K_DIM  512
#define GRID1  256             // one 1024-thread block per CU
#define NGRP   3125            // 50000 rows / 16 rows per wave-group
#define SB()   __builtin_amdgcn_sched_barrier(0)
// ws: float[256][33] per-block partials (plain stores, no atomics)

typedef __attribute__((ext_vector_type(8))) short bf16x8;
typedef __attribute__((ext_vector_type(4))) float f32x4;

// split 8 f32 into truncated-bf16 hi + bf16(residual) lo  (validated R2-R7: absmax 0.0)
__device__ __forceinline__ void split8(float4 a, float4 b, bf16x8& hi, bf16x8& lo) {
    float v[8] = {a.x, a.y, a.z, a.w, b.x, b.y, b.z, b.w};
    #pragma unroll
    for (int j = 0; j < 8; ++j) {
        unsigned u  = __float_as_uint(v[j]);
        unsigned hb = u & 0xFFFF0000u;
        float    lf = v[j] - __uint_as_float(hb);
        hi[j] = (short)(hb >> 16);
        lo[j] = (short)(__float_as_uint(lf) >> 16);
    }
}

__global__ __launch_bounds__(1024) void k_part(
    const float* __restrict__ other,   // [L][512]
    const float* __restrict__ W12,     // [32][512]
    const float* __restrict__ b12,     // [32]
    const float* __restrict__ Wa,      // [96]
    float* __restrict__ ws)            // [256][33]
{
    // W12 pre-split hi/lo, frag unit r = kc*4+g (k-permuted, validated R4-R7),
    // slot-swizzled: phys = r*32 + (ch ^ (r&31))  -> conflict-free writes AND reads
    __shared__ short whi[16384];       // 32 KB
    __shared__ short wlo[16384];       // 32 KB
    __shared__ float sbuf[16][34];

    const int tid  = threadIdx.x;
    const int lane = tid & 63;
    const int wv   = tid >> 6;         // 0..15
    const int cl   = lane & 15;
    const int g    = lane >> 4;

    // ---- one-time per CU: W12 -> LDS pre-split (2 frag-units per thread) ----
    #pragma unroll
    for (int c2 = 0; c2 < 2; ++c2) {
        const int u  = tid + c2 * 1024;          // unit: ch = u>>6, r = u&63
        const int ch = u >> 6, r = u & 63;       // r = kc*4+gg
        const float* wp = W12 + (size_t)ch * K_DIM + (r >> 2) * 32 + (r & 3) * 4;
        const float4 f0 = *(const float4*)wp;
        const float4 f1 = *(const float4*)(wp + 16);
        bf16x8 h8, l8; split8(f0, f1, h8, l8);
        const int p = (r * 32 + (ch ^ (r & 31))) * 8;
        *(bf16x8*)&whi[p] = h8;
        *(bf16x8*)&wlo[p] = l8;
    }
    __syncthreads();

    float rps = 0.f, rm0 = 0.f, rm1 = 0.f;       // per-lane partials
    const int wid = blockIdx.x * 16 + wv;        // global wave id = group id

    if (wid < NGRP) {
        const float b0 = b12[cl],     b1 = b12[16 + cl];
        const float w0 = Wa[64 + cl], w1 = Wa[80 + cl];  // shift-invariance: rx·Wa, ba dropped

        // lane (g,cl): row = wid*16+cl (always < 50000), k-window g*4 within each 16
        const float* xp = other + (size_t)(wid * 16 + cl) * K_DIM + (g << 2);
        float4 Q0[8], Q1[8];                     // named bufs: static indexing only

        #define ISSUE8(dst, q) do {                                            \
            _Pragma("unroll")                                                  \
            for (int i = 0; i < 8; ++i)                                        \
                dst[i] = *(const float4*)(xp + (q) * 128 + (i >> 1) * 32 + (i & 1) * 16); \
        } while (0)

        f32x4 acc0 = {0.f,0.f,0.f,0.f}, acc1 = {0.f,0.f,0.f,0.f};

        #define CONSUME8(buf, q) do {                                          \
            _Pragma("unroll")                                                  \
            for (int kk = 0; kk < 4; ++kk) {                                   \
                const int kc = (q) * 4 + kk;                                   \
                bf16x8 ah, al; split8(buf[kk * 2], buf[kk * 2 + 1], ah, al);   \
                const int r  = kc * 4 + g;                                     \
                const int u0 = (r * 32 + (cl ^ (r & 31))) * 8;                 \
                const bf16x8 bh0 = *(const bf16x8*)&whi[u0];                   \
                const bf16x8 bl0 = *(const bf16x8*)&wlo[u0];                   \
                const bf16x8 bh1 = *(const bf16x8*)&whi[u0 ^ 128];             \
                const bf16x8 bl1 = *(const bf16x8*)&wlo[u0 ^ 128];             \
                acc0 = __builtin_amdgcn_mfma_f32_16x16x32_bf16(ah, bh0, acc0, 0, 0, 0); \
                acc0 = __builtin_amdgcn_mfma_f32_16x16x32_bf16(al, bh0, acc0, 0, 0, 0); \
                acc0 = __builtin_amdgcn_mfma_f32_16x16x32_bf16(ah, bl0, acc0, 0, 0, 0); \
                acc1 = __builtin_amdgcn_mfma_f32_16x16x32_bf16(ah, bh1, acc1, 0, 0, 0); \
                acc1 = __builtin_amdgcn_mfma_f32_16x16x32_bf16(al, bh1, acc1, 0, 0, 0); \
                acc1 = __builtin_amdgcn_mfma_f32_16x16x32_bf16(ah, bl1, acc1, 0, 0, 0); \
            }                                                                  \
        } while (0)

        ISSUE8(Q0, 0); SB();
        ISSUE8(Q1, 1); SB();
        CONSUME8(Q0, 0);
        ISSUE8(Q0, 2); SB();
        CONSUME8(Q1, 1);
        ISSUE8(Q1, 3); SB();
        CONSUME8(Q0, 2);
        CONSUME8(Q1, 3);

        // ---- epilogue (validated): C row=(g*4+i), col=cl ----
        float e0[4], e1[4], s4[4];
        #pragma unroll
        for (int i = 0; i < 4; ++i) {
            e0[i] = acc0[i] + b0;
            e1[i] = acc1[i] + b1;
            s4[i] = fmaxf(e0[i], 0.f) * w0 + fmaxf(e1[i], 0.f) * w1;
        }
        #pragma unroll
        for (int d = 1; d < 16; d <<= 1) {
            #pragma unroll
            for (int i = 0; i < 4; ++i) s4[i] += __shfl_xor(s4[i], d);
        }
        #pragma unroll
        for (int i = 0; i < 4; ++i) {
            const float p = __expf(s4[i]);       // all rows valid: 3125*16 == 50000
            rps += p;
            rm0 = fmaf(p, e0[i], rm0);
            rm1 = fmaf(p, e1[i], rm1);
        }
    }

    // ---- block reduce: one plain store of 33 partials ----
    rps += __shfl_xor(rps, 16); rps += __shfl_xor(rps, 32);
    rm0 += __shfl_xor(rm0, 16); rm0 += __shfl_xor(rm0, 32);
    rm1 += __shfl_xor(rm1, 16); rm1 += __shfl_xor(rm1, 32);
    if (lane == 0)  sbuf[wv][0] = rps;
    if (lane < 16) { sbuf[wv][1 + cl] = rm0; sbuf[wv][17 + cl] = rm1; }
    __syncthreads();
    if (wv == 0 && lane < 33) {
        float v = 0.f;
        #pragma unroll
        for (int s = 0; s < 16; ++s) v += sbuf[s][lane];
        ws[blockIdx.x * 33 + lane] = v;
    }
}

__global__ __launch_bounds__(256) void k_final(
    const float* __restrict__ ws,       // [256][33]
    const float* __restrict__ inputs,   // [256]
    const float* __restrict__ act_idx,  // [64]
    const float* __restrict__ W11, const float* __restrict__ b11,
    const float* __restrict__ Wao, const float* __restrict__ bao,
    const float* __restrict__ W2,  const float* __restrict__ b2,
    const float* __restrict__ W3,  const float* __restrict__ b3,
    float* __restrict__ out)            // [33]: r, samples[32]
{
    __shared__ float wsl[33];
    __shared__ float rm[32], z[32], xcat[96], h64[64];
    __shared__ int   amax;

    const int t = threadIdx.x, hh = t >> 2, q = t & 3;
    if (t < 33) {                        // prior-kernel stores visible at kernel boundary
        float v = 0.f;
        for (int s = 0; s < GRID1; ++s) v += ws[s * 33 + t];
        wsl[t] = v;
    }
    __syncthreads();
    if (t < 32) rm[t] = fmaxf(wsl[1 + t] / wsl[0], 0.f);

    float bp = 0.f;
    for (int i = 0; i < 80; ++i) {
        const int k = q * 80 + i;
        const float xv = (k < 256) ? inputs[k] : act_idx[k - 256];
        bp = fmaf(W11[hh * 320 + k], xv, bp);
    }
    bp += __shfl_xor(bp, 1);
    bp += __shfl_xor(bp, 2);
    __syncthreads();

    if (t < 32) {
        float zz = bao[t];
        for (int d = 0; d < 32; ++d) zz = fmaf(Wao[t * 32 + d], rm[d], zz);
        z[t] = zz;
    }
    __syncthreads();
    if (t == 0) {
        int bi = 0; float bv = z[0];
        for (int c = 1; c < 32; ++c) { if (z[c] > bv) { bv = z[c]; bi = c; } }
        amax = bi;                                    // first-max, matches jnp.argmax
    }
    __syncthreads();
    if (q == 0) xcat[hh] = fmaxf(bp + b11[hh], 0.f);
    if (t < 32) xcat[64 + t] = (t == amax) ? 1.f : 0.f;   // one_hot_st == samples
    __syncthreads();

    float dp = 0.f;
    for (int i = 0; i < 24; ++i) {
        const int k = q * 24 + i;
        dp = fmaf(W2[hh * 96 + k], xcat[k], dp);
    }
    dp += __shfl_xor(dp, 1);
    dp += __shfl_xor(dp, 2);
    if (q == 0) h64[hh] = fmaxf(dp + b2[hh], 0.f);
    __syncthreads();

    if (t == 0) {
        float r = b3[0];
        for (int i = 0; i < 64; ++i) r = fmaf(W3[i], h64[i], r);
        out[0] = r;
    }
    if (t < 32) out[1 + t] = (t == amax) ? 1.f : 0.f;
}

extern "C" void kernel_launch(void* const* d_in, const int* in_sizes, int n_in,
                              void* d_out, int out_size, void* d_ws, size_t ws_size,
                              hipStream_t stream) {
    const float* inputs  = (const float*)d_in[0];
    const float* act_idx = (const float*)d_in[1];
    const float* other   = (const float*)d_in[2];
    const float* W11     = (const float*)d_in[3];
    const float* b11     = (const float*)d_in[4];
    const float* W12     = (const float*)d_in[5];
    const float* b12     = (const float*)d_in[6];
    const float* Wa      = (const float*)d_in[7];
    // d_in[8] = ba : unused (softmax shift-invariant)
    const float* Wao     = (const float*)d_in[9];
    const float* bao     = (const float*)d_in[10];
    const float* W2      = (const float*)d_in[11];
    const float* b2      = (const float*)d_in[12];
    const float* W3      = (const float*)d_in[13];
    const float* b3      = (const float*)d_in[14];
    float* ws = (float*)d_ws;

    // every ws slot k_final reads is written by k_part -> no memset needed
    k_part<<<GRID1, 1024, 0, stream>>>(other, W12, b12, Wa, ws);
    k_final<<<1, 256, 0, stream>>>(ws, inputs, act_idx, W11, b11,
                                   Wao, bao, W2, b2, W3, b3, (float*)d_out);
}

// Round 9
// 32.447 us; speedup vs baseline: 4.1407x; 1.2058x over previous
//
#include <hip/hip_runtime.h>

#define L_N    50000
#define K_DIM  512
#define GRID1  256             // one 1024-thread block per CU
#define NGRP   3125            // 50000 rows / 16 rows per wave-group
#define SB()   __builtin_amdgcn_sched_barrier(0)
// ws layout: float[33][256]  (channel-major -> k_final reads contiguous rows)

typedef __attribute__((ext_vector_type(8))) short bf16x8;
typedef __attribute__((ext_vector_type(4))) float f32x4;

// split 8 f32 into truncated-bf16 hi + bf16(residual) lo  (validated R2-R8: absmax 0.0)
__device__ __forceinline__ void split8(float4 a, float4 b, bf16x8& hi, bf16x8& lo) {
    float v[8] = {a.x, a.y, a.z, a.w, b.x, b.y, b.z, b.w};
    #pragma unroll
    for (int j = 0; j < 8; ++j) {
        unsigned u  = __float_as_uint(v[j]);
        unsigned hb = u & 0xFFFF0000u;
        float    lf = v[j] - __uint_as_float(hb);
        hi[j] = (short)(hb >> 16);
        lo[j] = (short)(__float_as_uint(lf) >> 16);
    }
}

__global__ __launch_bounds__(1024) void k_part(
    const float* __restrict__ other,   // [L][512]
    const float* __restrict__ W12,     // [32][512]
    const float* __restrict__ b12,     // [32]
    const float* __restrict__ Wa,      // [96]
    float* __restrict__ ws)            // [33][256]
{
    // W12 pre-split hi/lo, frag unit r = kc*4+g (k-permuted, validated R4-R8),
    // slot-swizzled: phys = r*32 + (ch ^ (r&31))
    __shared__ short whi[16384];       // 32 KB
    __shared__ short wlo[16384];       // 32 KB
    __shared__ float sbuf[16][34];

    const int tid  = threadIdx.x;
    const int lane = tid & 63;
    const int wv   = tid >> 6;         // 0..15
    const int cl   = lane & 15;
    const int g    = lane >> 4;

    // ---- one-time per CU: W12 -> LDS pre-split (2 frag-units per thread) ----
    #pragma unroll
    for (int c2 = 0; c2 < 2; ++c2) {
        const int u  = tid + c2 * 1024;          // unit: ch = u>>6, r = u&63
        const int ch = u >> 6, r = u & 63;       // r = kc*4+gg
        const float* wp = W12 + (size_t)ch * K_DIM + (r >> 2) * 32 + (r & 3) * 4;
        const float4 f0 = *(const float4*)wp;
        const float4 f1 = *(const float4*)(wp + 16);
        bf16x8 h8, l8; split8(f0, f1, h8, l8);
        const int p = (r * 32 + (ch ^ (r & 31))) * 8;
        *(bf16x8*)&whi[p] = h8;
        *(bf16x8*)&wlo[p] = l8;
    }
    __syncthreads();

    float rps = 0.f, rm0 = 0.f, rm1 = 0.f;       // per-lane partials
    const int wid = blockIdx.x * 16 + wv;        // global wave id = group id

    if (wid < NGRP) {
        const float b0 = b12[cl],     b1 = b12[16 + cl];
        const float w0 = Wa[64 + cl], w1 = Wa[80 + cl];  // shift-invariance: rx·Wa, ba dropped

        // lane (g,cl): row = wid*16+cl (always < 50000), k-window g*4 within each 16
        const float* xp = other + (size_t)(wid * 16 + cl) * K_DIM + (g << 2);
        float4 Q0[4], Q1[4];                     // 32 VGPR total: no spill at cap 128

        #define ISSUE4(dst, q) do {                                            \
            _Pragma("unroll")                                                  \
            for (int i = 0; i < 4; ++i)                                        \
                dst[i] = *(const float4*)(xp + (q) * 64 + (i >> 1) * 32 + (i & 1) * 16); \
        } while (0)

        f32x4 acc0 = {0.f,0.f,0.f,0.f}, acc1 = {0.f,0.f,0.f,0.f};

        #define CONSUME4(buf, q) do {                                          \
            _Pragma("unroll")                                                  \
            for (int kk = 0; kk < 2; ++kk) {                                   \
                const int kc = (q) * 2 + kk;                                   \
                bf16x8 ah, al; split8(buf[kk * 2], buf[kk * 2 + 1], ah, al);   \
                const int r  = kc * 4 + g;                                     \
                const int u0 = (r * 32 + (cl ^ (r & 31))) * 8;                 \
                const bf16x8 bh0 = *(const bf16x8*)&whi[u0];                   \
                const bf16x8 bl0 = *(const bf16x8*)&wlo[u0];                   \
                const bf16x8 bh1 = *(const bf16x8*)&whi[u0 ^ 128];             \
                const bf16x8 bl1 = *(const bf16x8*)&wlo[u0 ^ 128];             \
                acc0 = __builtin_amdgcn_mfma_f32_16x16x32_bf16(ah, bh0, acc0, 0, 0, 0); \
                acc0 = __builtin_amdgcn_mfma_f32_16x16x32_bf16(al, bh0, acc0, 0, 0, 0); \
                acc0 = __builtin_amdgcn_mfma_f32_16x16x32_bf16(ah, bl0, acc0, 0, 0, 0); \
                acc1 = __builtin_amdgcn_mfma_f32_16x16x32_bf16(ah, bh1, acc1, 0, 0, 0); \
                acc1 = __builtin_amdgcn_mfma_f32_16x16x32_bf16(al, bh1, acc1, 0, 0, 0); \
                acc1 = __builtin_amdgcn_mfma_f32_16x16x32_bf16(ah, bl1, acc1, 0, 0, 0); \
            }                                                                  \
        } while (0)

        // rolling 2-deep quarter pipeline (4-8 loads in flight, zero spills)
        ISSUE4(Q0, 0); SB();
        ISSUE4(Q1, 1); SB();
        CONSUME4(Q0, 0); ISSUE4(Q0, 2); SB();
        CONSUME4(Q1, 1); ISSUE4(Q1, 3); SB();
        CONSUME4(Q0, 2); ISSUE4(Q0, 4); SB();
        CONSUME4(Q1, 3); ISSUE4(Q1, 5); SB();
        CONSUME4(Q0, 4); ISSUE4(Q0, 6); SB();
        CONSUME4(Q1, 5); ISSUE4(Q1, 7); SB();
        CONSUME4(Q0, 6);
        CONSUME4(Q1, 7);

        // ---- epilogue (validated): C row=(g*4+i), col=cl ----
        float e0[4], e1[4], s4[4];
        #pragma unroll
        for (int i = 0; i < 4; ++i) {
            e0[i] = acc0[i] + b0;
            e1[i] = acc1[i] + b1;
            s4[i] = fmaxf(e0[i], 0.f) * w0 + fmaxf(e1[i], 0.f) * w1;
        }
        #pragma unroll
        for (int d = 1; d < 16; d <<= 1) {
            #pragma unroll
            for (int i = 0; i < 4; ++i) s4[i] += __shfl_xor(s4[i], d);
        }
        #pragma unroll
        for (int i = 0; i < 4; ++i) {
            const float p = __expf(s4[i]);       // all rows valid: 3125*16 == 50000
            rps += p;
            rm0 = fmaf(p, e0[i], rm0);
            rm1 = fmaf(p, e1[i], rm1);
        }
    }

    // ---- block reduce: 33 plain stores (channel-major) ----
    rps += __shfl_xor(rps, 16); rps += __shfl_xor(rps, 32);
    rm0 += __shfl_xor(rm0, 16); rm0 += __shfl_xor(rm0, 32);
    rm1 += __shfl_xor(rm1, 16); rm1 += __shfl_xor(rm1, 32);
    if (lane == 0)  sbuf[wv][0] = rps;
    if (lane < 16) { sbuf[wv][1 + cl] = rm0; sbuf[wv][17 + cl] = rm1; }
    __syncthreads();
    if (wv == 0 && lane < 33) {
        float v = 0.f;
        #pragma unroll
        for (int s = 0; s < 16; ++s) v += sbuf[s][lane];
        ws[lane * GRID1 + blockIdx.x] = v;
    }
}

__global__ __launch_bounds__(256) void k_final(
    const float* __restrict__ ws,       // [33][256]
    const float* __restrict__ inputs,   // [256]
    const float* __restrict__ act_idx,  // [64]
    const float* __restrict__ W11, const float* __restrict__ b11,
    const float* __restrict__ Wao, const float* __restrict__ bao,
    const float* __restrict__ W2,  const float* __restrict__ b2,
    const float* __restrict__ W3,  const float* __restrict__ b3,
    float* __restrict__ out)            // [33]: r, samples[32]
{
    __shared__ float xsin[320];
    __shared__ float wsl[33];
    __shared__ float rm[32], z[32], xcat[96], h64[64];
    __shared__ int   amax;

    const int t = threadIdx.x, hh = t >> 2, q = t & 3;

    // parallel vectorized cross-block reduction: 132 threads, 64 floats each
    if (t < 132) {
        const int c = t >> 2, seg = t & 3;
        const float4* p = (const float4*)(ws + c * GRID1 + seg * 64);
        float v = 0.f;
        #pragma unroll
        for (int i = 0; i < 16; ++i) { const float4 f = p[i]; v += f.x + f.y + f.z + f.w; }
        v += __shfl_xor(v, 1);
        v += __shfl_xor(v, 2);
        if (seg == 0) wsl[c] = v;
    }
    // stage x_in = [inputs ; act_idx] in LDS
    xsin[t] = inputs[t];
    if (t < 64) xsin[256 + t] = act_idx[t];
    __syncthreads();

    if (t < 32) rm[t] = fmaxf(wsl[1 + t] / wsl[0], 0.f);

    // input_x: 4 threads per output h, 80 k each, float4 W11 loads
    float bp = 0.f;
    {
        const float4* wrow = (const float4*)(W11 + hh * 320 + q * 80);
        #pragma unroll
        for (int i = 0; i < 20; ++i) {
            const float4 f = wrow[i];
            const int k = q * 80 + i * 4;
            bp = fmaf(f.x, xsin[k], bp);
            bp = fmaf(f.y, xsin[k + 1], bp);
            bp = fmaf(f.z, xsin[k + 2], bp);
            bp = fmaf(f.w, xsin[k + 3], bp);
        }
    }
    bp += __shfl_xor(bp, 1);
    bp += __shfl_xor(bp, 2);
    __syncthreads();

    if (t < 32) {
        float zz = bao[t];
        for (int d = 0; d < 32; ++d) zz = fmaf(Wao[t * 32 + d], rm[d], zz);
        z[t] = zz;
    }
    __syncthreads();
    if (t == 0) {
        int bi = 0; float bv = z[0];
        for (int c = 1; c < 32; ++c) { if (z[c] > bv) { bv = z[c]; bi = c; } }
        amax = bi;                                    // first-max, matches jnp.argmax
    }
    __syncthreads();
    if (q == 0) xcat[hh] = fmaxf(bp + b11[hh], 0.f);
    if (t < 32) xcat[64 + t] = (t == amax) ? 1.f : 0.f;   // one_hot_st == samples
    __syncthreads();

    float dp = 0.f;
    for (int i = 0; i < 24; ++i) {
        const int k = q * 24 + i;
        dp = fmaf(W2[hh * 96 + k], xcat[k], dp);
    }
    dp += __shfl_xor(dp, 1);
    dp += __shfl_xor(dp, 2);
    if (q == 0) h64[hh] = fmaxf(dp + b2[hh], 0.f);
    __syncthreads();

    if (t == 0) {
        float r = b3[0];
        for (int i = 0; i < 64; ++i) r = fmaf(W3[i], h64[i], r);
        out[0] = r;
    }
    if (t < 32) out[1 + t] = (t == amax) ? 1.f : 0.f;
}

extern "C" void kernel_launch(void* const* d_in, const int* in_sizes, int n_in,
                              void* d_out, int out_size, void* d_ws, size_t ws_size,
                              hipStream_t stream) {
    const float* inputs  = (const float*)d_in[0];
    const float* act_idx = (const float*)d_in[1];
    const float* other   = (const float*)d_in[2];
    const float* W11     = (const float*)d_in[3];
    const float* b11     = (const float*)d_in[4];
    const float* W12     = (const float*)d_in[5];
    const float* b12     = (const float*)d_in[6];
    const float* Wa      = (const float*)d_in[7];
    // d_in[8] = ba : unused (softmax shift-invariant)
    const float* Wao     = (const float*)d_in[9];
    const float* bao     = (const float*)d_in[10];
    const float* W2      = (const float*)d_in[11];
    const float* b2      = (const float*)d_in[12];
    const float* W3      = (const float*)d_in[13];
    const float* b3      = (const float*)d_in[14];
    float* ws = (float*)d_ws;

    // every ws slot k_final reads is written by k_part -> no memset needed
    k_part<<<GRID1, 1024, 0, stream>>>(other, W12, b12, Wa, ws);
    k_final<<<1, 256, 0, stream>>>(ws, inputs, act_idx, W11, b11,
                                   Wao, bao, W2, b2, W3, b3, (float*)d_out);
}